// Round 13
// baseline (251.836 us; speedup 1.0000x reference)
//
#include <hip/hip_runtime.h>
#include <hip/hip_bf16.h>

#define BB 2
#define SS 2048
#define DD 1024
#define HH 16
#define DKK 64
// M = BB*SS = 4096, N = K = DD = 1024

typedef __hip_bfloat16 bf16;
typedef unsigned short u16;
using frag_ab = __attribute__((ext_vector_type(8))) short;  // 8 bf16 (4 VGPRs)
using frag_cd = __attribute__((ext_vector_type(4))) float;  // 4 fp32

__device__ inline u16 f2bf(float f) {
    bf16 h = __float2bfloat16(f);
    return *reinterpret_cast<u16*>(&h);
}

// raw hardware exp2: single trans-pipe instruction, no OCML range fixup.
// Inputs here are <= ~11; large negatives flush to 0 (desired for softmax).
__device__ inline float exp2_hw(float x) {
    float r;
    asm("v_exp_f32 %0, %1" : "=v"(r) : "v"(x));
    return r;
}

// pack two f32 -> 2 bf16 (v_cvt_pk_bf16_f32 via the sanctioned HIP intrinsic)
__device__ inline unsigned pk2bf(float a, float b) {
    __hip_bfloat162 h = __float22bfloat162_rn(float2{a, b});
    return *reinterpret_cast<unsigned*>(&h);
}

// async global->LDS, 16B per lane (lds dest = wave-uniform base + lane*16)
__device__ inline void gld16(const void* g, void* l) {
    __builtin_amdgcn_global_load_lds((const __attribute__((address_space(1))) void*)g,
                                     (__attribute__((address_space(3))) void*)l,
                                     16, 0, 0);
}

// XOR-swizzle for [64-row][64-u16] tiles (row stride 128 B == 32 banks).
// Operates on u16 indices; XORs the 16B-slot index (bits 3..5) with row&7.
// Involution: applied identically on write and read. Keeps 16B chunks intact.
__device__ inline int swz16(int idx) {
    return idx ^ (((idx >> 6) & 7) << 3);
}

// ---------------- prep: fp32->bf16 converts + mask tile flags ----------------
__global__ __launch_bounds__(256) void prep(
    const float* __restrict__ q, const float* __restrict__ k, const float* __restrict__ v,
    const float* __restrict__ Wq, const float* __restrict__ Wk,
    const float* __restrict__ Wv, const float* __restrict__ Wo,
    u16* __restrict__ qb, u16* __restrict__ kb, u16* __restrict__ vb,
    u16* __restrict__ Wqb, u16* __restrict__ Wkb, u16* __restrict__ Wvb, u16* __restrict__ Wob,
    const int* __restrict__ mask, int* __restrict__ flags) {
    int bid = blockIdx.x;
    int t = threadIdx.x;
    if (bid < 8192) {
        const float* src;
        u16* dst;
        int local;
        if (bid < 6144) {
            int ts = bid >> 11;
            local = bid & 2047;
            src = ts == 0 ? q : (ts == 1 ? k : v);
            dst = ts == 0 ? qb : (ts == 1 ? kb : vb);
        } else {
            int wsel = (bid - 6144) >> 9;
            local = (bid - 6144) & 511;
            src = wsel == 0 ? Wq : (wsel == 1 ? Wk : (wsel == 2 ? Wv : Wo));
            dst = wsel == 0 ? Wqb : (wsel == 1 ? Wkb : (wsel == 2 ? Wvb : Wob));
        }
        size_t base = (size_t)local * 2048 + t * 8;
        float4 a = *(const float4*)&src[base];
        float4 b = *(const float4*)&src[base + 4];
        ushort4 u0, u1;
        u0.x = f2bf(a.x); u0.y = f2bf(a.y); u0.z = f2bf(a.z); u0.w = f2bf(a.w);
        u1.x = f2bf(b.x); u1.y = f2bf(b.y); u1.z = f2bf(b.z); u1.w = f2bf(b.w);
        *(ushort4*)&dst[base] = u0;
        *(ushort4*)&dst[base + 4] = u1;
    } else {
        int tile = bid - 8192;
        int qt = tile >> 5, kt = tile & 31;
        __shared__ int f;
        if (t == 0) f = 0;
        __syncthreads();
        int qq = qt * 64 + (t >> 2);
        const int4* row = (const int4*)(mask + (size_t)qq * SS + kt * 64 + (t & 3) * 16);
        int anyz = 0;
#pragma unroll
        for (int i = 0; i < 4; ++i) {
            int4 m4 = row[i];
            anyz |= (m4.x == 0) | (m4.y == 0) | (m4.z == 0) | (m4.w == 0);
        }
        if (anyz) f = 1;
        __syncthreads();
        if (t == 0) flags[tile] = f;
    }
}

// ---------------- fused QKV GEMM (bf16 in, bf16 out) ----------------
// z==0 (Q) scale folds in 1/sqrt(DK) AND log2(e) so attention softmax can use
// exp2 directly (v_exp_f32 computes 2^x; __expf costs an extra v_mul each).
__global__ __launch_bounds__(256) void qkv_gemm(
    const u16* __restrict__ Aq, const u16* __restrict__ Ak, const u16* __restrict__ Av,
    const u16* __restrict__ Wq, const u16* __restrict__ Wk, const u16* __restrict__ Wv,
    const float* __restrict__ bq, const float* __restrict__ bk, const float* __restrict__ bv,
    u16* __restrict__ Qo, u16* __restrict__ Ko, u16* __restrict__ Vo) {
    __shared__ u16 As[128 * 32];
    __shared__ u16 Bs[128 * 32];

    int z = blockIdx.z;
    const u16* A = z == 0 ? Aq : (z == 1 ? Ak : Av);
    const u16* W = z == 0 ? Wq : (z == 1 ? Wk : Wv);
    const float* bias = z == 0 ? bq : (z == 1 ? bk : bv);
    u16* out = z == 0 ? Qo : (z == 1 ? Ko : Vo);

    int t = threadIdx.x;
    int m0 = blockIdx.y * 128;
    int n0 = blockIdx.x * 128;
    int w = t >> 6, lane = t & 63;
    int quad = lane >> 4, l16 = lane & 15;
    int wm = w >> 1, wn = w & 1;

    const u16* Ab = A + (size_t)m0 * DD;
    const u16* Wb = W + (size_t)n0 * DD;

    frag_cd acc[4][4];
#pragma unroll
    for (int mt = 0; mt < 4; ++mt)
#pragma unroll
        for (int nt = 0; nt < 4; ++nt) acc[mt][nt] = frag_cd{0.f, 0.f, 0.f, 0.f};

    for (int k0 = 0; k0 < DD; k0 += 32) {
        if (k0) __syncthreads();
#pragma unroll
        for (int i = 0; i < 2; ++i) {
            int c = t + i * 256;
            int row = c >> 2, kc = (c & 3) * 8;
            gld16(Ab + (size_t)row * DD + k0 + kc, &As[c * 8]);
            gld16(Wb + (size_t)row * DD + k0 + kc, &Bs[c * 8]);
        }
        __syncthreads();

        frag_ab af[4], bfr[4];
#pragma unroll
        for (int mt = 0; mt < 4; ++mt)
            af[mt] = *(const frag_ab*)&As[(wm * 64 + mt * 16 + l16) * 32 + quad * 8];
#pragma unroll
        for (int nt = 0; nt < 4; ++nt)
            bfr[nt] = *(const frag_ab*)&Bs[(wn * 64 + nt * 16 + l16) * 32 + quad * 8];
#pragma unroll
        for (int mt = 0; mt < 4; ++mt)
#pragma unroll
            for (int nt = 0; nt < 4; ++nt)
                acc[mt][nt] = __builtin_amdgcn_mfma_f32_16x16x32_bf16(
                    af[mt], bfr[nt], acc[mt][nt], 0, 0, 0);
    }

    // 0.125 * log2(e) for Q (exp2-domain softmax), 1.0 for K/V
    float scale = z == 0 ? 0.18033688f : 1.0f;
#pragma unroll
    for (int nt = 0; nt < 4; ++nt) {
        int n = n0 + wn * 64 + nt * 16 + l16;
        float bv_ = bias[n];
        int h_ = n >> 6, d_ = n & 63;
#pragma unroll
        for (int mt = 0; mt < 4; ++mt) {
            int mb = m0 + wm * 64 + mt * 16 + quad * 4;
            int b_ = mb >> 11, s_ = mb & 2047;
            if (z == 2) {
                ushort4 u;
                u.x = f2bf(acc[mt][nt][0] + bv_);
                u.y = f2bf(acc[mt][nt][1] + bv_);
                u.z = f2bf(acc[mt][nt][2] + bv_);
                u.w = f2bf(acc[mt][nt][3] + bv_);
                *(ushort4*)&out[((size_t)(b_ * HH + h_) * DKK + d_) * SS + s_] = u;
            } else {
#pragma unroll
                for (int r = 0; r < 4; ++r)
                    out[((size_t)(b_ * HH + h_) * SS + s_ + r) * DKK + d_] =
                        f2bf((acc[mt][nt][r] + bv_) * scale);
            }
        }
    }
}

// ---------------- output GEMM: fp32 out = Cw(bf16) @ Wo^T + bo ----------------
// R12: tile 128x64, grid 16x32 = 512 blocks = 2 blocks/CU (was 1). Kept.
__global__ __launch_bounds__(256) void out_gemm(const u16* __restrict__ A,
                                                const u16* __restrict__ W,
                                                const float* __restrict__ bias,
                                                float* __restrict__ out) {
    __shared__ u16 As[128 * 32];
    __shared__ u16 Bs[64 * 32];

    int t = threadIdx.x;
    int m0 = blockIdx.y * 128;
    int n0 = blockIdx.x * 64;
    int w = t >> 6, lane = t & 63;
    int quad = lane >> 4, l16 = lane & 15;
    int wm = w >> 1, wn = w & 1;

    const u16* Ab = A + (size_t)m0 * DD;
    const u16* Wb = W + (size_t)n0 * DD;

    frag_cd acc[4][2];
#pragma unroll
    for (int mt = 0; mt < 4; ++mt)
#pragma unroll
        for (int nt = 0; nt < 2; ++nt) acc[mt][nt] = frag_cd{0.f, 0.f, 0.f, 0.f};

    for (int k0 = 0; k0 < DD; k0 += 32) {
        if (k0) __syncthreads();
#pragma unroll
        for (int i = 0; i < 2; ++i) {
            int c = t + i * 256;
            int row = c >> 2, kc = (c & 3) * 8;
            gld16(Ab + (size_t)row * DD + k0 + kc, &As[c * 8]);
        }
        {
            int row = t >> 2, kc = (t & 3) * 8;
            gld16(Wb + (size_t)row * DD + k0 + kc, &Bs[t * 8]);
        }
        __syncthreads();

        frag_ab af[4], bfr[2];
#pragma unroll
        for (int mt = 0; mt < 4; ++mt)
            af[mt] = *(const frag_ab*)&As[(wm * 64 + mt * 16 + l16) * 32 + quad * 8];
#pragma unroll
        for (int nt = 0; nt < 2; ++nt)
            bfr[nt] = *(const frag_ab*)&Bs[(wn * 32 + nt * 16 + l16) * 32 + quad * 8];
#pragma unroll
        for (int mt = 0; mt < 4; ++mt)
#pragma unroll
            for (int nt = 0; nt < 2; ++nt)
                acc[mt][nt] = __builtin_amdgcn_mfma_f32_16x16x32_bf16(
                    af[mt], bfr[nt], acc[mt][nt], 0, 0, 0);
    }

#pragma unroll
    for (int nt = 0; nt < 2; ++nt) {
        int n = n0 + wn * 32 + nt * 16 + l16;
        float bv_ = bias[n];
#pragma unroll
        for (int mt = 0; mt < 4; ++mt) {
            int mb = m0 + wm * 64 + mt * 16 + quad * 4;
#pragma unroll
            for (int r = 0; r < 4; ++r)
                out[(size_t)(mb + r) * DD + n] = acc[mt][nt][r] + bv_;
        }
    }
}

// ---------------- flash attention: 128-q tile, 4 waves x 32 q (2 groups), shared frags ----------------
// Grid: B*H*(S/128) = 512 blocks, 256 threads (4 waves). Wave w owns q columns
// {q0 + w*32 + g*16 + l16 : g=0,1}. S^T = K·Q^T (col=l16=q, row=quad*4+r=key).
// R13: LDS-traffic cut without R10's confounds. The K/V A-fragment reads are
// HOISTED and shared across both q-groups (R0's original 2-group layout
// re-read them per group; R1's 8-wave split duplicated them 8x). Per tile:
// QK A-reads 64->32KB, PV A-reads 64->32KB => 176->112 KB total (0.64x),
// with the identical conflict-free 16x16 swizzled read pattern, same MFMA
// count, same LDS footprint (34816B), same grid (2 blocks/CU).
// Cost: waves/SIMD 4->2 (R1 measured that direction at only ~5%).
// Prior proven layers: XOR-swizzle (R0), T13 defer-rescale + T5 setprio (R6),
// MFMA row-sum l + max3 tree + azmask (R7), exp2_hw + pk2bf + incremental
// pointers (R11), exp2-domain softmax (Q pre-scaled by 0.125*log2e).
__global__ __launch_bounds__(256) void attn_mfma(const u16* __restrict__ Qb,
                                                 const u16* __restrict__ Kb,
                                                 const u16* __restrict__ Vb,
                                                 const int* __restrict__ mask,
                                                 const int* __restrict__ flags,
                                                 u16* __restrict__ C) {
    __shared__ u16 Ks[64 * 64];      // [key][d], swizzled
    __shared__ u16 Vt[64 * 64];      // [d][key], swizzled
    __shared__ u16 Pw[4][2][16 * 72];// per-wave, per-group P^T [q][key]

    int blk = blockIdx.x;
    int Qt = blk & 15;          // q-128-tile index
    int bh = blk >> 4;
    int h = bh & 15;
    int b = bh >> 4;
    int q0 = Qt * 128;

    const u16* Kg = Kb + (size_t)bh * SS * DKK;
    const u16* Vg = Vb + (size_t)bh * DKK * SS;

    int t = threadIdx.x;
    int w = t >> 6;
    int lane = t & 63;
    int quad = lane >> 4;
    int l16 = lane & 15;

    // ---- Q B-frags direct from global (one-time, per group) ----
    frag_ab bq[2][2];
#pragma unroll
    for (int g = 0; g < 2; ++g) {
        const u16* Qr = Qb + ((size_t)bh * SS + q0 + w * 32 + g * 16 + l16) * DKK;
        bq[g][0] = *(const frag_ab*)&Qr[quad * 8];
        bq[g][1] = *(const frag_ab*)&Qr[32 + quad * 8];
    }

    // all-ones bf16 A-fragment for the MFMA row-sum (bf16 1.0 = 0x3F80)
    frag_ab ones;
#pragma unroll
    for (int j = 0; j < 8; ++j) ones[j] = (short)0x3F80;

    frag_cd o[2][4];
    frag_cd lacc[2];
#pragma unroll
    for (int g = 0; g < 2; ++g) {
#pragma unroll
        for (int dt = 0; dt < 4; ++dt) o[g][dt] = frag_cd{0.f, 0.f, 0.f, 0.f};
        lacc[g] = frag_cd{0.f, 0.f, 0.f, 0.f};
    }
    float m_prev[2] = {-1e30f, -1e30f};

    // staging geometry: two int4 (16B) chunks per thread for each of K and V
    int vd0 = t >> 3;
    int vc0 = (t & 7) * 8;
    int fbase = (Qt * 2 + (w >> 1)) * 32;   // flags row for this wave's 64-q half

    // ---- prologue: flags bitmask + incremental staging pointers ----
    unsigned azmask = 0;
#pragma unroll
    for (int i = 0; i < 32; ++i) azmask |= (flags[fbase + i] != 0 ? 1u : 0u) << i;

    const int4* kptr = (const int4*)Kg + t;            // += 512 per tile (8KB)
    const u16*  vptr0 = Vg + (size_t)vd0 * SS + vc0;   // += 64 per tile
    const u16*  vptr1 = Vg + (size_t)(vd0 + 32) * SS + vc0;

    int4 kr0 = kptr[0];
    int4 kr1 = kptr[256];
    int4 vr0 = *(const int4*)vptr0;
    int4 vr1 = *(const int4*)vptr1;

    for (int kt = 0; kt < 32; ++kt) {
        if (kt) __syncthreads();  // (A) prior tile's frag reads complete
        *(int4*)&Ks[swz16(8 * t)] = kr0;
        *(int4*)&Ks[swz16(8 * (t + 256))] = kr1;
        *(int4*)&Vt[swz16(vd0 * 64 + vc0)] = vr0;
        *(int4*)&Vt[swz16((vd0 + 32) * 64 + vc0)] = vr1;
        if (kt < 31) {
            kptr += 512;
            vptr0 += 64;
            vptr1 += 64;
            kr0 = kptr[0];
            kr1 = kptr[256];
            vr0 = *(const int4*)vptr0;
            vr1 = *(const int4*)vptr1;
        }
        __syncthreads();  // (B) staged tile visible

        // ---- S^T = K_tile · Q^T (K frags read ONCE, used by both groups) ----
        float s[2][4][4];
        __builtin_amdgcn_s_setprio(1);
#pragma unroll
        for (int nt = 0; nt < 4; ++nt) {
            int kr = nt * 16 + l16;
            frag_ab ak0 = *(const frag_ab*)&Ks[swz16(kr * 64 + quad * 8)];
            frag_ab ak1 = *(const frag_ab*)&Ks[swz16(kr * 64 + 32 + quad * 8)];
#pragma unroll
            for (int g = 0; g < 2; ++g) {
                frag_cd sf = frag_cd{0.f, 0.f, 0.f, 0.f};
                sf = __builtin_amdgcn_mfma_f32_16x16x32_bf16(ak0, bq[g][0], sf, 0, 0, 0);
                sf = __builtin_amdgcn_mfma_f32_16x16x32_bf16(ak1, bq[g][1], sf, 0, 0, 0);
#pragma unroll
                for (int r = 0; r < 4; ++r) s[g][nt][r] = sf[r];
            }
        }
        __builtin_amdgcn_s_setprio(0);

        if ((azmask >> kt) & 1) {
#pragma unroll
            for (int g = 0; g < 2; ++g) {
                int qg = q0 + w * 32 + g * 16 + l16;
#pragma unroll
                for (int nt = 0; nt < 4; ++nt)
#pragma unroll
                    for (int r = 0; r < 4; ++r) {
                        int kg = kt * 64 + nt * 16 + quad * 4 + r;
                        if (mask[(size_t)qg * SS + kg] == 0) s[g][nt][r] = -1e9f;
                    }
            }
        }

        // ---- online softmax per group (exp2 domain, T13 defer-rescale) ----
#pragma unroll
        for (int g = 0; g < 2; ++g) {
            float m0_ = fmaxf(fmaxf(s[g][0][0], s[g][0][1]), fmaxf(s[g][0][2], s[g][0][3]));
            float m1_ = fmaxf(fmaxf(s[g][1][0], s[g][1][1]), fmaxf(s[g][1][2], s[g][1][3]));
            float m2_ = fmaxf(fmaxf(s[g][2][0], s[g][2][1]), fmaxf(s[g][2][2], s[g][2][3]));
            float m3_ = fmaxf(fmaxf(s[g][3][0], s[g][3][1]), fmaxf(s[g][3][2], s[g][3][3]));
            float mc = fmaxf(fmaxf(m0_, m1_), fmaxf(m2_, m3_));
            mc = fmaxf(mc, __shfl_xor(mc, 16));
            mc = fmaxf(mc, __shfl_xor(mc, 32));
            if (!__all(mc <= m_prev[g] + 11.f)) {
                float mnew = fmaxf(m_prev[g], mc);
                float alpha = exp2_hw(m_prev[g] - mnew);
#pragma unroll
                for (int r = 0; r < 4; ++r) lacc[g][r] *= alpha;
#pragma unroll
                for (int dt = 0; dt < 4; ++dt)
#pragma unroll
                    for (int r = 0; r < 4; ++r) o[g][dt][r] *= alpha;
                m_prev[g] = mnew;
            }

#pragma unroll
            for (int nt = 0; nt < 4; ++nt) {
                uint2 up;
                up.x = pk2bf(exp2_hw(s[g][nt][0] - m_prev[g]), exp2_hw(s[g][nt][1] - m_prev[g]));
                up.y = pk2bf(exp2_hw(s[g][nt][2] - m_prev[g]), exp2_hw(s[g][nt][3] - m_prev[g]));
                *(uint2*)&Pw[w][g][l16 * 72 + nt * 16 + quad * 4] = up;
            }
        }

        frag_ab bp[2][2];
#pragma unroll
        for (int g = 0; g < 2; ++g) {
            bp[g][0] = *(const frag_ab*)&Pw[w][g][l16 * 72 + quad * 8];
            bp[g][1] = *(const frag_ab*)&Pw[w][g][l16 * 72 + 32 + quad * 8];
        }

        // ---- O^T += V^T · P^T (V frags read ONCE, used by both groups) ----
        __builtin_amdgcn_s_setprio(1);
#pragma unroll
        for (int g = 0; g < 2; ++g) {
            lacc[g] = __builtin_amdgcn_mfma_f32_16x16x32_bf16(ones, bp[g][0], lacc[g], 0, 0, 0);
            lacc[g] = __builtin_amdgcn_mfma_f32_16x16x32_bf16(ones, bp[g][1], lacc[g], 0, 0, 0);
        }
#pragma unroll
        for (int dt = 0; dt < 4; ++dt) {
            int dr = dt * 16 + l16;
            frag_ab av0 = *(const frag_ab*)&Vt[swz16(dr * 64 + quad * 8)];
            frag_ab av1 = *(const frag_ab*)&Vt[swz16(dr * 64 + 32 + quad * 8)];
#pragma unroll
            for (int g = 0; g < 2; ++g) {
                o[g][dt] = __builtin_amdgcn_mfma_f32_16x16x32_bf16(av0, bp[g][0], o[g][dt], 0, 0, 0);
                o[g][dt] = __builtin_amdgcn_mfma_f32_16x16x32_bf16(av1, bp[g][1], o[g][dt], 0, 0, 0);
            }
        }
        __builtin_amdgcn_s_setprio(0);
    }

    // ---- epilogue: bf16 [B,S,D] (paired converts) ----
#pragma unroll
    for (int g = 0; g < 2; ++g) {
        float inv = 1.f / lacc[g][0];   // all lacc rows equal = l[q=l16]
        int qg = q0 + w * 32 + g * 16 + l16;
        u16* Crow = C + ((size_t)b * SS + qg) * DD + h * 64;
#pragma unroll
        for (int dt = 0; dt < 4; ++dt) {
            uint2 u;
            u.x = pk2bf(o[g][dt][0] * inv, o[g][dt][1] * inv);
            u.y = pk2bf(o[g][dt][2] * inv, o[g][dt][3] * inv);
            *(uint2*)&Crow[dt * 16 + quad * 4] = u;
        }
    }
}

extern "C" void kernel_launch(void* const* d_in, const int* in_sizes, int n_in,
                              void* d_out, int out_size, void* d_ws, size_t ws_size,
                              hipStream_t stream) {
    const float* q = (const float*)d_in[0];
    const float* k = (const float*)d_in[1];
    const float* v = (const float*)d_in[2];
    const int* mask = (const int*)d_in[3];
    const float* Wq = (const float*)d_in[4];
    const float* bq = (const float*)d_in[5];
    const float* Wk = (const float*)d_in[6];
    const float* bk = (const float*)d_in[7];
    const float* Wv = (const float*)d_in[8];
    const float* bv = (const float*)d_in[9];
    const float* Wo = (const float*)d_in[10];
    const float* bo = (const float*)d_in[11];
    float* out = (float*)d_out;

    const size_t MB = 1024u * 1024u;
    char* ws = (char*)d_ws;
    u16* qb = (u16*)(ws + 0 * MB);     // 8 MB (reused as Cw after qkv_gemm)
    u16* kb = (u16*)(ws + 8 * MB);
    u16* vb = (u16*)(ws + 16 * MB);
    u16* Wqb = (u16*)(ws + 24 * MB);
    u16* Wkb = (u16*)(ws + 26 * MB);
    u16* Wvb = (u16*)(ws + 28 * MB);
    u16* Wob = (u16*)(ws + 30 * MB);
    u16* Qb = (u16*)(ws + 32 * MB);
    u16* Kb = (u16*)(ws + 40 * MB);
    u16* Vb = (u16*)(ws + 48 * MB);
    int* flags = (int*)(ws + 56 * MB);
    u16* Cw = qb;

    prep<<<9216, 256, 0, stream>>>(q, k, v, Wq, Wk, Wv, Wo,
                                   qb, kb, vb, Wqb, Wkb, Wvb, Wob, mask, flags);

    dim3 grid(DD / 128, (BB * SS) / 128, 3);
    qkv_gemm<<<grid, 256, 0, stream>>>(qb, kb, vb, Wqb, Wkb, Wvb,
                                       bq, bk, bv, Qb, Kb, Vb);

    attn_mfma<<<BB * HH * (SS / 128), 256, 0, stream>>>(Qb, Kb, Vb, mask, flags, Cw);

    out_gemm<<<dim3(DD / 64, (BB * SS) / 128), 256, 0, stream>>>(Cw, Wob, bo, out);
}

// Round 14
// 242.679 us; speedup vs baseline: 1.0377x; 1.0377x over previous
//
#include <hip/hip_runtime.h>
#include <hip/hip_bf16.h>

#define BB 2
#define SS 2048
#define DD 1024
#define HH 16
#define DKK 64
// M = BB*SS = 4096, N = K = DD = 1024

typedef __hip_bfloat16 bf16;
typedef unsigned short u16;
using frag_ab = __attribute__((ext_vector_type(8))) short;  // 8 bf16 (4 VGPRs)
using frag_cd = __attribute__((ext_vector_type(4))) float;  // 4 fp32

__device__ inline u16 f2bf(float f) {
    bf16 h = __float2bfloat16(f);
    return *reinterpret_cast<u16*>(&h);
}

// raw hardware exp2: single trans-pipe instruction, no OCML range fixup.
// Inputs here are <= ~11; large negatives flush to 0 (desired for softmax).
__device__ inline float exp2_hw(float x) {
    float r;
    asm("v_exp_f32 %0, %1" : "=v"(r) : "v"(x));
    return r;
}

// pack two f32 -> 2 bf16 (v_cvt_pk_bf16_f32 via the sanctioned HIP intrinsic)
__device__ inline unsigned pk2bf(float a, float b) {
    __hip_bfloat162 h = __float22bfloat162_rn(float2{a, b});
    return *reinterpret_cast<unsigned*>(&h);
}

// async global->LDS, 16B per lane (lds dest = wave-uniform base + lane*16)
__device__ inline void gld16(const void* g, void* l) {
    __builtin_amdgcn_global_load_lds((const __attribute__((address_space(1))) void*)g,
                                     (__attribute__((address_space(3))) void*)l,
                                     16, 0, 0);
}

// XOR-swizzle for tiles with 64-u16 (128 B) rows: XOR the 16B-slot index
// (bits 3..5) with row&7. Involution; with global_load_lds the involution is
// applied on the per-lane GLOBAL source address (LDS dest stays linear) and
// on the LDS read index (rule #21 both-sides pattern).
__device__ inline int swz16(int idx) {
    return idx ^ (((idx >> 6) & 7) << 3);
}

// ---------------- prep: fp32->bf16 converts + mask tile flags ----------------
__global__ __launch_bounds__(256) void prep(
    const float* __restrict__ q, const float* __restrict__ k, const float* __restrict__ v,
    const float* __restrict__ Wq, const float* __restrict__ Wk,
    const float* __restrict__ Wv, const float* __restrict__ Wo,
    u16* __restrict__ qb, u16* __restrict__ kb, u16* __restrict__ vb,
    u16* __restrict__ Wqb, u16* __restrict__ Wkb, u16* __restrict__ Wvb, u16* __restrict__ Wob,
    const int* __restrict__ mask, int* __restrict__ flags) {
    int bid = blockIdx.x;
    int t = threadIdx.x;
    if (bid < 8192) {
        const float* src;
        u16* dst;
        int local;
        if (bid < 6144) {
            int ts = bid >> 11;
            local = bid & 2047;
            src = ts == 0 ? q : (ts == 1 ? k : v);
            dst = ts == 0 ? qb : (ts == 1 ? kb : vb);
        } else {
            int wsel = (bid - 6144) >> 9;
            local = (bid - 6144) & 511;
            src = wsel == 0 ? Wq : (wsel == 1 ? Wk : (wsel == 2 ? Wv : Wo));
            dst = wsel == 0 ? Wqb : (wsel == 1 ? Wkb : (wsel == 2 ? Wvb : Wob));
        }
        size_t base = (size_t)local * 2048 + t * 8;
        float4 a = *(const float4*)&src[base];
        float4 b = *(const float4*)&src[base + 4];
        ushort4 u0, u1;
        u0.x = f2bf(a.x); u0.y = f2bf(a.y); u0.z = f2bf(a.z); u0.w = f2bf(a.w);
        u1.x = f2bf(b.x); u1.y = f2bf(b.y); u1.z = f2bf(b.z); u1.w = f2bf(b.w);
        *(ushort4*)&dst[base] = u0;
        *(ushort4*)&dst[base + 4] = u1;
    } else {
        int tile = bid - 8192;
        int qt = tile >> 5, kt = tile & 31;
        __shared__ int f;
        if (t == 0) f = 0;
        __syncthreads();
        int qq = qt * 64 + (t >> 2);
        const int4* row = (const int4*)(mask + (size_t)qq * SS + kt * 64 + (t & 3) * 16);
        int anyz = 0;
#pragma unroll
        for (int i = 0; i < 4; ++i) {
            int4 m4 = row[i];
            anyz |= (m4.x == 0) | (m4.y == 0) | (m4.z == 0) | (m4.w == 0);
        }
        if (anyz) f = 1;
        __syncthreads();
        if (t == 0) flags[tile] = f;
    }
}

// ---------------- fused QKV GEMM (bf16 in, bf16 out) ----------------
// R14: BK 32 -> 64 (K-steps 32 -> 16) halves the per-K-step vmcnt(0)+barrier
// drains (~20% of m97-structure cycles). LDS 32 KB (still 3 blocks/CU; the
// m132 BK=128 failure was the 64KB -> 2 blocks/CU cliff). The [128][64] tile
// has 128B rows (32-bank alias) -> swz16 swizzle via PRE-SWIZZLED global
// source (gld16 writes linearly; involution on source + read, rule #21).
// z==0 (Q) scale folds in 1/sqrt(DK) AND log2(e) for exp2-domain softmax.
__global__ __launch_bounds__(256) void qkv_gemm(
    const u16* __restrict__ Aq, const u16* __restrict__ Ak, const u16* __restrict__ Av,
    const u16* __restrict__ Wq, const u16* __restrict__ Wk, const u16* __restrict__ Wv,
    const float* __restrict__ bq, const float* __restrict__ bk, const float* __restrict__ bv,
    u16* __restrict__ Qo, u16* __restrict__ Ko, u16* __restrict__ Vo) {
    __shared__ u16 As[128 * 64];
    __shared__ u16 Bs[128 * 64];

    int z = blockIdx.z;
    const u16* A = z == 0 ? Aq : (z == 1 ? Ak : Av);
    const u16* W = z == 0 ? Wq : (z == 1 ? Wk : Wv);
    const float* bias = z == 0 ? bq : (z == 1 ? bk : bv);
    u16* out = z == 0 ? Qo : (z == 1 ? Ko : Vo);

    int t = threadIdx.x;
    int m0 = blockIdx.y * 128;
    int n0 = blockIdx.x * 128;
    int w = t >> 6, lane = t & 63;
    int quad = lane >> 4, l16 = lane & 15;
    int wm = w >> 1, wn = w & 1;

    const u16* Ab = A + (size_t)m0 * DD;
    const u16* Wb = W + (size_t)n0 * DD;

    frag_cd acc[4][4];
#pragma unroll
    for (int mt = 0; mt < 4; ++mt)
#pragma unroll
        for (int nt = 0; nt < 4; ++nt) acc[mt][nt] = frag_cd{0.f, 0.f, 0.f, 0.f};

    for (int k0 = 0; k0 < DD; k0 += 64) {
        if (k0) __syncthreads();
#pragma unroll
        for (int i = 0; i < 4; ++i) {
            int c = t + i * 256;
            int row = c >> 3, sl = c & 7;
            int src = (sl ^ (row & 7)) * 8;      // inverse-swizzled source chunk
            gld16(Ab + (size_t)row * DD + k0 + src, &As[c * 8]);
            gld16(Wb + (size_t)row * DD + k0 + src, &Bs[c * 8]);
        }
        __syncthreads();

#pragma unroll
        for (int kk = 0; kk < 2; ++kk) {
            frag_ab af[4], bfr[4];
#pragma unroll
            for (int mt = 0; mt < 4; ++mt)
                af[mt] = *(const frag_ab*)&As[swz16((wm * 64 + mt * 16 + l16) * 64 + kk * 32 + quad * 8)];
#pragma unroll
            for (int nt = 0; nt < 4; ++nt)
                bfr[nt] = *(const frag_ab*)&Bs[swz16((wn * 64 + nt * 16 + l16) * 64 + kk * 32 + quad * 8)];
#pragma unroll
            for (int mt = 0; mt < 4; ++mt)
#pragma unroll
                for (int nt = 0; nt < 4; ++nt)
                    acc[mt][nt] = __builtin_amdgcn_mfma_f32_16x16x32_bf16(
                        af[mt], bfr[nt], acc[mt][nt], 0, 0, 0);
        }
    }

    // 0.125 * log2(e) for Q (exp2-domain softmax), 1.0 for K/V
    float scale = z == 0 ? 0.18033688f : 1.0f;
#pragma unroll
    for (int nt = 0; nt < 4; ++nt) {
        int n = n0 + wn * 64 + nt * 16 + l16;
        float bv_ = bias[n];
        int h_ = n >> 6, d_ = n & 63;
#pragma unroll
        for (int mt = 0; mt < 4; ++mt) {
            int mb = m0 + wm * 64 + mt * 16 + quad * 4;
            int b_ = mb >> 11, s_ = mb & 2047;
            if (z == 2) {
                ushort4 u;
                u.x = f2bf(acc[mt][nt][0] + bv_);
                u.y = f2bf(acc[mt][nt][1] + bv_);
                u.z = f2bf(acc[mt][nt][2] + bv_);
                u.w = f2bf(acc[mt][nt][3] + bv_);
                *(ushort4*)&out[((size_t)(b_ * HH + h_) * DKK + d_) * SS + s_] = u;
            } else {
#pragma unroll
                for (int r = 0; r < 4; ++r)
                    out[((size_t)(b_ * HH + h_) * SS + s_ + r) * DKK + d_] =
                        f2bf((acc[mt][nt][r] + bv_) * scale);
            }
        }
    }
}

// ---------------- output GEMM: fp32 out = Cw(bf16) @ Wo^T + bo ----------------
// R12: tile 128x64, grid 16x32 = 512 blocks = 2 blocks/CU (was 1). Kept.
__global__ __launch_bounds__(256) void out_gemm(const u16* __restrict__ A,
                                                const u16* __restrict__ W,
                                                const float* __restrict__ bias,
                                                float* __restrict__ out) {
    __shared__ u16 As[128 * 32];
    __shared__ u16 Bs[64 * 32];

    int t = threadIdx.x;
    int m0 = blockIdx.y * 128;
    int n0 = blockIdx.x * 64;
    int w = t >> 6, lane = t & 63;
    int quad = lane >> 4, l16 = lane & 15;
    int wm = w >> 1, wn = w & 1;

    const u16* Ab = A + (size_t)m0 * DD;
    const u16* Wb = W + (size_t)n0 * DD;

    frag_cd acc[4][2];
#pragma unroll
    for (int mt = 0; mt < 4; ++mt)
#pragma unroll
        for (int nt = 0; nt < 2; ++nt) acc[mt][nt] = frag_cd{0.f, 0.f, 0.f, 0.f};

    for (int k0 = 0; k0 < DD; k0 += 32) {
        if (k0) __syncthreads();
#pragma unroll
        for (int i = 0; i < 2; ++i) {
            int c = t + i * 256;
            int row = c >> 2, kc = (c & 3) * 8;
            gld16(Ab + (size_t)row * DD + k0 + kc, &As[c * 8]);
        }
        {
            int row = t >> 2, kc = (t & 3) * 8;
            gld16(Wb + (size_t)row * DD + k0 + kc, &Bs[t * 8]);
        }
        __syncthreads();

        frag_ab af[4], bfr[2];
#pragma unroll
        for (int mt = 0; mt < 4; ++mt)
            af[mt] = *(const frag_ab*)&As[(wm * 64 + mt * 16 + l16) * 32 + quad * 8];
#pragma unroll
        for (int nt = 0; nt < 2; ++nt)
            bfr[nt] = *(const frag_ab*)&Bs[(wn * 32 + nt * 16 + l16) * 32 + quad * 8];
#pragma unroll
        for (int mt = 0; mt < 4; ++mt)
#pragma unroll
            for (int nt = 0; nt < 2; ++nt)
                acc[mt][nt] = __builtin_amdgcn_mfma_f32_16x16x32_bf16(
                    af[mt], bfr[nt], acc[mt][nt], 0, 0, 0);
    }

#pragma unroll
    for (int nt = 0; nt < 2; ++nt) {
        int n = n0 + wn * 32 + nt * 16 + l16;
        float bv_ = bias[n];
#pragma unroll
        for (int mt = 0; mt < 4; ++mt) {
            int mb = m0 + wm * 64 + mt * 16 + quad * 4;
#pragma unroll
            for (int r = 0; r < 4; ++r)
                out[(size_t)(mb + r) * DD + n] = acc[mt][nt][r] + bv_;
        }
    }
}

// ---------------- flash attention: 128-q tile, 8 waves, 1 softmax chain per wave ----------------
// Grid: B*H*(S/128) = 512 blocks, 512 threads (8 waves). Wave w owns q columns
// {q0 + w*16 + l16}. S^T = K·Q^T (col=l16=q, row=quad*4+r=key).
// R14 = R11 attn verbatim (best measured: 61.8-66us across runs). R13's
// frag-sharing regressed (72.8us: occupancy 36->18.6, VGPR 56->120) — 4th
// falsified LDS-traffic/occupancy trade; this structure is the balanced
// operating point. Layers: XOR-swizzle (R0), 8-wave (R1), T13 defer-rescale +
// T5 setprio (R6), MFMA row-sum l + max3 tree + azmask (R7), exp2_hw +
// pk2bf + incremental pointers (R11), exp2-domain softmax (Q pre-scaled).
__global__ __launch_bounds__(512) void attn_mfma(const u16* __restrict__ Qb,
                                                 const u16* __restrict__ Kb,
                                                 const u16* __restrict__ Vb,
                                                 const int* __restrict__ mask,
                                                 const int* __restrict__ flags,
                                                 u16* __restrict__ C) {
    __shared__ u16 Ks[64 * 64];      // [key][d], swizzled
    __shared__ u16 Vt[64 * 64];      // [d][key], swizzled
    __shared__ u16 Pw[8][16 * 72];   // per-wave P^T [q][key] (stride 72 -> 2-way, free)

    int blk = blockIdx.x;
    int Qt = blk & 15;          // q-128-tile index
    int bh = blk >> 4;
    int h = bh & 15;
    int b = bh >> 4;
    int q0 = Qt * 128;

    const u16* Kg = Kb + (size_t)bh * SS * DKK;
    const u16* Vg = Vb + (size_t)bh * DKK * SS;

    int t = threadIdx.x;
    int w = t >> 6;
    int lane = t & 63;
    int quad = lane >> 4;
    int l16 = lane & 15;

    // ---- Q B-frags direct from global (one-time) ----
    frag_ab bq0, bq1;
    {
        const u16* Qr = Qb + ((size_t)bh * SS + q0 + w * 16 + l16) * DKK;
        bq0 = *(const frag_ab*)&Qr[quad * 8];
        bq1 = *(const frag_ab*)&Qr[32 + quad * 8];
    }

    // all-ones bf16 A-fragment for the MFMA row-sum (bf16 1.0 = 0x3F80)
    frag_ab ones;
#pragma unroll
    for (int j = 0; j < 8; ++j) ones[j] = (short)0x3F80;

    frag_cd o[4];
#pragma unroll
    for (int dt = 0; dt < 4; ++dt) o[dt] = frag_cd{0.f, 0.f, 0.f, 0.f};
    frag_cd lacc = frag_cd{0.f, 0.f, 0.f, 0.f};   // running row-sum l (all rows equal)
    float m_prev = -1e30f;

    // staging geometry: one int4 (16B) per thread for each of K and V
    int vd = t >> 3;
    int vc = (t & 7) * 8;
    int fbase = (Qt * 2 + (w >> 2)) * 32;   // flags row for this wave's 64-q half

    // ---- prologue: flags bitmask + incremental staging pointers ----
    unsigned azmask = 0;
#pragma unroll
    for (int i = 0; i < 32; ++i) azmask |= (flags[fbase + i] != 0 ? 1u : 0u) << i;

    const int4* kptr = (const int4*)Kg + t;            // += 512 per tile (8KB)
    const u16*  vptr = Vg + (size_t)vd * SS + vc;      // += 64 per tile

    int4 kr0 = *kptr;
    int4 vr0 = *(const int4*)vptr;

    for (int kt = 0; kt < 32; ++kt) {
        if (kt) __syncthreads();  // (A) prior tile's frag reads complete
        *(int4*)&Ks[swz16(8 * t)] = kr0;
        *(int4*)&Vt[swz16(vd * 64 + vc)] = vr0;
        if (kt < 31) {
            kptr += 512;
            vptr += 64;
            kr0 = *kptr;
            vr0 = *(const int4*)vptr;
        }
        __syncthreads();  // (B) staged tile visible

        // ---- S^T = K_tile · Q^T ----
        float s[4][4];
        __builtin_amdgcn_s_setprio(1);
#pragma unroll
        for (int nt = 0; nt < 4; ++nt) {
            int kr = nt * 16 + l16;
            frag_ab ak0 = *(const frag_ab*)&Ks[swz16(kr * 64 + quad * 8)];
            frag_ab ak1 = *(const frag_ab*)&Ks[swz16(kr * 64 + 32 + quad * 8)];
            frag_cd sf = frag_cd{0.f, 0.f, 0.f, 0.f};
            sf = __builtin_amdgcn_mfma_f32_16x16x32_bf16(ak0, bq0, sf, 0, 0, 0);
            sf = __builtin_amdgcn_mfma_f32_16x16x32_bf16(ak1, bq1, sf, 0, 0, 0);
#pragma unroll
            for (int r = 0; r < 4; ++r) s[nt][r] = sf[r];
        }
        __builtin_amdgcn_s_setprio(0);

        if ((azmask >> kt) & 1) {
            int qg = q0 + w * 16 + l16;
#pragma unroll
            for (int nt = 0; nt < 4; ++nt)
#pragma unroll
                for (int r = 0; r < 4; ++r) {
                    int kg = kt * 64 + nt * 16 + quad * 4 + r;
                    if (mask[(size_t)qg * SS + kg] == 0) s[nt][r] = -1e9f;
                }
        }

        // ---- online softmax (exp2 domain, T13 defer-rescale, max3 tree) ----
        float m0_ = fmaxf(fmaxf(s[0][0], s[0][1]), fmaxf(s[0][2], s[0][3]));
        float m1_ = fmaxf(fmaxf(s[1][0], s[1][1]), fmaxf(s[1][2], s[1][3]));
        float m2_ = fmaxf(fmaxf(s[2][0], s[2][1]), fmaxf(s[2][2], s[2][3]));
        float m3_ = fmaxf(fmaxf(s[3][0], s[3][1]), fmaxf(s[3][2], s[3][3]));
        float mc = fmaxf(fmaxf(m0_, m1_), fmaxf(m2_, m3_));
        mc = fmaxf(mc, __shfl_xor(mc, 16));
        mc = fmaxf(mc, __shfl_xor(mc, 32));
        if (!__all(mc <= m_prev + 11.f)) {
            float mnew = fmaxf(m_prev, mc);
            float alpha = exp2_hw(m_prev - mnew);
#pragma unroll
            for (int r = 0; r < 4; ++r) lacc[r] *= alpha;
#pragma unroll
            for (int dt = 0; dt < 4; ++dt)
#pragma unroll
                for (int r = 0; r < 4; ++r) o[dt][r] *= alpha;
            m_prev = mnew;
        }

        float p[4][4];
#pragma unroll
        for (int nt = 0; nt < 4; ++nt)
#pragma unroll
            for (int r = 0; r < 4; ++r)
                p[nt][r] = exp2_hw(s[nt][r] - m_prev);

        // ---- P^T round-trip (paired bf16 converts) ----
#pragma unroll
        for (int nt = 0; nt < 4; ++nt) {
            uint2 up;
            up.x = pk2bf(p[nt][0], p[nt][1]);
            up.y = pk2bf(p[nt][2], p[nt][3]);
            *(uint2*)&Pw[w][l16 * 72 + nt * 16 + quad * 4] = up;
        }
        frag_ab bp0 = *(const frag_ab*)&Pw[w][l16 * 72 + quad * 8];
        frag_ab bp1 = *(const frag_ab*)&Pw[w][l16 * 72 + 32 + quad * 8];

        // ---- O^T += V^T · P^T, and l += ones · P^T (row-sum on MFMA pipe) ----
        __builtin_amdgcn_s_setprio(1);
        lacc = __builtin_amdgcn_mfma_f32_16x16x32_bf16(ones, bp0, lacc, 0, 0, 0);
        lacc = __builtin_amdgcn_mfma_f32_16x16x32_bf16(ones, bp1, lacc, 0, 0, 0);
#pragma unroll
        for (int dt = 0; dt < 4; ++dt) {
            int dr = dt * 16 + l16;
            frag_ab av0 = *(const frag_ab*)&Vt[swz16(dr * 64 + quad * 8)];
            frag_ab av1 = *(const frag_ab*)&Vt[swz16(dr * 64 + 32 + quad * 8)];
            o[dt] = __builtin_amdgcn_mfma_f32_16x16x32_bf16(av0, bp0, o[dt], 0, 0, 0);
            o[dt] = __builtin_amdgcn_mfma_f32_16x16x32_bf16(av1, bp1, o[dt], 0, 0, 0);
        }
        __builtin_amdgcn_s_setprio(0);
    }

    // ---- epilogue: bf16 [B,S,D] (paired converts) ----
    {
        float inv = 1.f / lacc[0];   // all lacc rows equal = l[q=l16]
        int qg = q0 + w * 16 + l16;
        u16* Crow = C + ((size_t)b * SS + qg) * DD + h * 64;
#pragma unroll
        for (int dt = 0; dt < 4; ++dt) {
            uint2 u;
            u.x = pk2bf(o[dt][0] * inv, o[dt][1] * inv);
            u.y = pk2bf(o[dt][2] * inv, o[dt][3] * inv);
            *(uint2*)&Crow[dt * 16 + quad * 4] = u;
        }
    }
}

extern "C" void kernel_launch(void* const* d_in, const int* in_sizes, int n_in,
                              void* d_out, int out_size, void* d_ws, size_t ws_size,
                              hipStream_t stream) {
    const float* q = (const float*)d_in[0];
    const float* k = (const float*)d_in[1];
    const float* v = (const float*)d_in[2];
    const int* mask = (const int*)d_in[3];
    const float* Wq = (const float*)d_in[4];
    const float* bq = (const float*)d_in[5];
    const float* Wk = (const float*)d_in[6];
    const float* bk = (const float*)d_in[7];
    const float* Wv = (const float*)d_in[8];
    const float* bv = (const float*)d_in[9];
    const float* Wo = (const float*)d_in[10];
    const float* bo = (const float*)d_in[11];
    float* out = (float*)d_out;

    const size_t MB = 1024u * 1024u;
    char* ws = (char*)d_ws;
    u16* qb = (u16*)(ws + 0 * MB);     // 8 MB (reused as Cw after qkv_gemm)
    u16* kb = (u16*)(ws + 8 * MB);
    u16* vb = (u16*)(ws + 16 * MB);
    u16* Wqb = (u16*)(ws + 24 * MB);
    u16* Wkb = (u16*)(ws + 26 * MB);
    u16* Wvb = (u16*)(ws + 28 * MB);
    u16* Wob = (u16*)(ws + 30 * MB);
    u16* Qb = (u16*)(ws + 32 * MB);
    u16* Kb = (u16*)(ws + 40 * MB);
    u16* Vb = (u16*)(ws + 48 * MB);
    int* flags = (int*)(ws + 56 * MB);
    u16* Cw = qb;

    prep<<<9216, 256, 0, stream>>>(q, k, v, Wq, Wk, Wv, Wo,
                                   qb, kb, vb, Wqb, Wkb, Wvb, Wob, mask, flags);

    dim3 grid(DD / 128, (BB * SS) / 128, 3);
    qkv_gemm<<<grid, 256, 0, stream>>>(qb, kb, vb, Wqb, Wkb, Wvb,
                                       bq, bk, bv, Qb, Kb, Vb);

    attn_mfma<<<BB * HH * (SS / 128), 512, 0, stream>>>(Qb, Kb, Vb, mask, flags, Cw);

    out_gemm<<<dim3(DD / 64, (BB * SS) / 128), 256, 0, stream>>>(Cw, Wob, bo, out);
}